// Round 9
// baseline (598.149 us; speedup 1.0000x reference)
//
#include <hip/hip_runtime.h>
#include <cstdint>
#include <cstddef>

#define B_ 64
#define S_ 2048
#define H_ 512
#define R_ 256
#define M_ (B_ * S_)   // 131072
#define NEGV (-1.0e9f)

typedef short short8 __attribute__((ext_vector_type(8)));
typedef unsigned short u16x8 __attribute__((ext_vector_type(8)));
typedef float f32x4 __attribute__((ext_vector_type(4)));
typedef unsigned short u16;

#define VMCNT(N)  asm volatile("s_waitcnt vmcnt(" #N ")" ::: "memory")

// ---------- helpers ----------
__device__ __forceinline__ u16 f2b(float x) {
    union { float f; uint32_t u; } c; c.f = x;
    uint32_t u = c.u;
    uint32_t r = (u + 0x7fffu + ((u >> 16) & 1u)) >> 16;   // RNE
    return (u16)r;
}
__device__ __forceinline__ float b2f(u16 u) {
    union { uint32_t u; float f; } c; c.u = ((uint32_t)u) << 16;
    return c.f;
}
// HW packed f32->bf16 (RNE, identical result to f2b)
__device__ __forceinline__ uint32_t pk2(float lo, float hi) {
    uint32_t r;
    asm("v_cvt_pk_bf16_f32 %0, %1, %2" : "=v"(r) : "v"(lo), "v"(hi));
    return r;
}
__device__ __forceinline__ void load_lds16(const void* g, void* l) {
    __builtin_amdgcn_global_load_lds((__attribute__((address_space(1))) void*)g,
                                     (__attribute__((address_space(3))) void*)l,
                                     16, 0, 0);
}

// ---------- K1: base[b,k] = rel@Wr^T + Wr_b + pool@Wg^T + Wg_b + Wh_b  (+ Wh_w f32->bf16) ----------
__global__ void k_base(const float* __restrict__ rel, const float* __restrict__ pool,
                       const float* __restrict__ Wg_w, const float* __restrict__ Wg_b,
                       const float* __restrict__ Wh_b,
                       const float* __restrict__ Wr_w, const float* __restrict__ Wr_b,
                       const float* __restrict__ whw, float* __restrict__ base,
                       u16* __restrict__ whwb) {
    int tid = threadIdx.x;
    {   // convert Wh_w: 262144 elems = 65536 float4 groups; exactly one per thread
        int gi = blockIdx.x * 256 + tid;
        float4 v = ((const float4*)whw)[gi];
        ushort4 o; o.x = f2b(v.x); o.y = f2b(v.y); o.z = f2b(v.z); o.w = f2b(v.w);
        ((ushort4*)whwb)[gi] = o;
    }
    int b = blockIdx.x >> 2, q = blockIdx.x & 3;
    __shared__ __attribute__((aligned(16))) float srel[R_];
    __shared__ __attribute__((aligned(16))) float spool[H_];
    __shared__ float accs[128];
    srel[tid & 255] = rel[b * R_ + (tid & 255)];
    for (int i = tid; i < H_; i += 256) spool[i] = pool[b * H_ + i];
    __syncthreads();
    int kk = tid & 127, half = tid >> 7;
    int k = q * 128 + kk;
    float acc = 0.f;
    if (half == 0) {
        acc = Wr_b[k] + Wg_b[k] + Wh_b[k];
        const float4* wr = (const float4*)(Wr_w + (size_t)k * R_);
        #pragma unroll 8
        for (int r4 = 0; r4 < R_ / 4; ++r4) {
            float4 w = wr[r4]; float4 x = ((const float4*)srel)[r4];
            acc += w.x * x.x + w.y * x.y + w.z * x.z + w.w * x.w;
        }
        const float4* wg = (const float4*)(Wg_w + (size_t)k * H_);
        #pragma unroll 8
        for (int h4 = 0; h4 < 32; ++h4) {
            float4 w = wg[h4]; float4 x = ((const float4*)spool)[h4];
            acc += w.x * x.x + w.y * x.y + w.z * x.z + w.w * x.w;
        }
    } else {
        const float4* wg = (const float4*)(Wg_w + (size_t)k * H_);
        #pragma unroll 8
        for (int h4 = 32; h4 < 128; ++h4) {
            float4 w = wg[h4]; float4 x = ((const float4*)spool)[h4];
            acc += w.x * x.x + w.y * x.y + w.z * x.z + w.w * x.w;
        }
    }
    if (half) accs[kk] = acc;
    __syncthreads();
    if (!half) base[b * H_ + k] = acc + accs[kk];
}

// ---------- K2: main GEMM [M,512]x[512,512]^T + tanh/alpha epilogue -> partial[4][M] ----------
// v8: TRIPLE-buffered all-global_load_lds pipeline with counted vmcnt (T3+T4).
//  - A staged as RAW F32 via global_load_lds (fire-and-forget, no reg round-trip, no
//    WRITE_A chain for the allocator to sink). bf16 conversion happens at fragment-read
//    time: 2x ds_read_b128 + 4x v_cvt_pk_bf16_f32 per fragment (~16 VALU/step).
//  - 3 LDS buffers: S(kt+2) issued at TOP of step kt -> every stage gets a ~2-step
//    (>800cy) load->use window. Pre-barrier wait = vmcnt(6): own-wave S(kt+1) done,
//    S(kt+2)'s 6 loads stay in flight ACROSS the barrier. Queue never drained till tail.
//  - A LDS layout per 16-row chunk: [2 halves][64 lanes][16B] -> gload_lds write side
//    AND ds_read side both lane-linear stride-16 (canonical m97 pattern, conflict-free).
//  - No ds_writes anywhere in the loop -> raw s_barrier needs no lgkmcnt.
// Ledger/wave/step: A 4 instr (2 chunks x 2 halves) + B 2 = 6. LDS 73 KB -> 2 blocks/CU.
__launch_bounds__(256)
__global__ void k_gemm(const float* __restrict__ A32,  // [M, 512] f32 (sent_h)
                       const u16* __restrict__ Bw,     // [512, 512] bf16 (Wh_w, B^T layout)
                       const float* __restrict__ base,  // [B_, H_]
                       const float* __restrict__ alpha, // [H_]
                       float* __restrict__ partial)     // [4][M]
{
    const int K = 512;
    const int NT = 16;                  // K-steps (BK=32)
    int j = blockIdx.x;
    int xcd  = j & 7;
    int slot = j >> 3;
    int nb   = slot & 3;
    int mb   = (slot >> 2) * 8 + xcd;   // 0..1023, bijective over grid 4096
    int m0 = mb * 128;
    int n0 = nb * 128;
    int b  = m0 >> 11;   // m0 / S_

    int tid = threadIdx.x;
    int w  = tid >> 6;      // wave 0..3
    int l  = tid & 63;
    int wm = w & 1, wn = w >> 1;
    int lr = l & 15;        // frag row within 16-row chunk / C col
    int lq = l >> 4;        // quad

    // A: 3 bufs x 8 chunks x (2 halves x 64 lanes x 4 f32) = 3 x 16 KB
    __shared__ __attribute__((aligned(16))) float smA[3][8 * 512];
    // B: 3 bufs x 8 chunks x (64 lanes x 8 bf16)            = 3 x 8 KB
    __shared__ __attribute__((aligned(16))) u16   smB[3][8 * 512];
    __shared__ float red[2][2][64];                                 // 1 KB

    f32x4 zero = {0.f, 0.f, 0.f, 0.f};
    f32x4 acc[4][4];
    #pragma unroll
    for (int i = 0; i < 4; ++i)
        #pragma unroll
        for (int jj = 0; jj < 4; ++jj) acc[i][jj] = zero;

    // stage one BK=32 slab (A f32 16KB + B bf16 8KB) into buffer `buf`.
    // Wave w stages chunks 2w, 2w+1. 6 gload_lds per wave.
    auto STAGE = [&](int buf, int kt) {
        int k0 = kt * 32;
        #pragma unroll
        for (int i = 0; i < 2; ++i) {
            int c = w * 2 + i;
            // A chunk c, halves h=0,1: lane l <- row c*16+(l&15), cols k0+(l>>4)*8+h*4 (4 f32)
            #pragma unroll
            for (int h = 0; h < 2; ++h) {
                const float* ga = A32 + (size_t)(m0 + c * 16 + lr) * K + k0 + lq * 8 + h * 4;
                load_lds16(ga, &smA[buf][c * 512 + h * 256]);
            }
            // B chunk c: lane l <- row n0+c*16+(l&15), cols k0+(l>>4)*8 (8 bf16)
            const u16* gb = Bw + (size_t)(n0 + c * 16 + lr) * K + k0 + lq * 8;
            load_lds16(gb, &smB[buf][c * 512]);
        }
    };

    // prologue: queue = S0(6) + S1(6)
    STAGE(0, 0);
    STAGE(1, 1);
    VMCNT(6);                          // S0 landed; S1 rides
    __builtin_amdgcn_s_barrier();
    __builtin_amdgcn_sched_barrier(0);

    #pragma unroll
    for (int kt = 0; kt < NT; ++kt) {
        const int cur = kt % 3;
        if (kt < NT - 2) STAGE((kt + 2) % 3, kt + 2);   // queue: S(kt+1)[6] + S(kt+2)[6]
        __builtin_amdgcn_s_setprio(1);
        {
            // A fragments: f32 from LDS -> cvt_pk -> bf16x8
            short8 af[4], bf[4];
            #pragma unroll
            for (int mi = 0; mi < 4; ++mi) {
                const float* ca = &smA[cur][(wm * 4 + mi) * 512];
                f32x4 lo = *(const f32x4*)(ca + l * 4);
                f32x4 hi = *(const f32x4*)(ca + 256 + l * 4);
                uint32_t d0 = pk2(lo[0], lo[1]);
                uint32_t d1 = pk2(lo[2], lo[3]);
                uint32_t d2 = pk2(hi[0], hi[1]);
                uint32_t d3 = pk2(hi[2], hi[3]);
                uint4 uv = make_uint4(d0, d1, d2, d3);
                af[mi] = *(short8*)&uv;
            }
            #pragma unroll
            for (int ni = 0; ni < 4; ++ni)
                bf[ni] = *(const short8*)(&smB[cur][(wn * 4 + ni) * 512] + l * 8);
            #pragma unroll
            for (int mi = 0; mi < 4; ++mi)
                #pragma unroll
                for (int ni = 0; ni < 4; ++ni)
                    acc[mi][ni] = __builtin_amdgcn_mfma_f32_16x16x32_bf16(af[mi], bf[ni], acc[mi][ni], 0, 0, 0);
        }
        __builtin_amdgcn_s_setprio(0);
        if (kt < NT - 1) {
            if (kt < NT - 2) { VMCNT(6); } else { VMCNT(0); }   // S(kt+1) landed
            __builtin_amdgcn_s_barrier();
            __builtin_amdgcn_sched_barrier(0);
        }
    }

    // epilogue: sum_n tanh(acc + base[b,n]) * alpha[n] = sum(a) - sum 2a/(exp2(C2*v)+1)
    const float C2 = 2.8853900817779268f;   // 2*log2(e)
    float base2[4], a2[4];
    float asum = 0.f;
    #pragma unroll
    for (int ni = 0; ni < 4; ++ni) {
        int n = n0 + wn * 64 + ni * 16 + lr;
        base2[ni] = C2 * base[b * H_ + n];
        float al  = alpha[n];
        a2[ni] = 2.0f * al;
        asum  += al;
    }
    #pragma unroll
    for (int mi = 0; mi < 4; ++mi) {
        #pragma unroll
        for (int r = 0; r < 4; ++r) {
            float s = asum;
            #pragma unroll
            for (int ni = 0; ni < 4; ++ni) {
                float f  = fmaf(acc[mi][ni][r], C2, base2[ni]);
                float e  = __builtin_amdgcn_exp2f(f);
                float rr = __builtin_amdgcn_rcpf(e + 1.0f);
                s = fmaf(-a2[ni], rr, s);
            }
            s += __shfl_xor(s, 1);
            s += __shfl_xor(s, 2);
            s += __shfl_xor(s, 4);
            s += __shfl_xor(s, 8);
            if (lr == 0) red[wm][wn][mi * 16 + lq * 4 + r] = s;
        }
    }
    __syncthreads();
    if (tid < 128) {
        int wmi = tid >> 6, row = tid & 63;
        float sum = red[wmi][0][row] + red[wmi][1][row];
        partial[(size_t)nb * M_ + m0 + wmi * 64 + row] = sum;
    }
}

// ---------- K3: softmax over S per b ----------
__global__ void k_softmax(const float* __restrict__ partial, const int* __restrict__ mask,
                          const float* __restrict__ alpha_b, float* __restrict__ wout) {
    int b = blockIdx.x;
    int tid = threadIdx.x;
    __shared__ float sred[8];
    float x[8];
    float ab = alpha_b[0];
    float lmax = -3.0e38f;
    #pragma unroll
    for (int jj = 0; jj < 8; ++jj) {
        int s = tid + jj * 256;
        size_t m = (size_t)b * S_ + s;
        float v = partial[m] + partial[(size_t)M_ + m] + partial[2 * (size_t)M_ + m] + partial[3 * (size_t)M_ + m] + ab;
        if (mask[b * S_ + s] == 0) v = NEGV;
        x[jj] = v;
        lmax = fmaxf(lmax, v);
    }
    #pragma unroll
    for (int off = 1; off < 64; off <<= 1) lmax = fmaxf(lmax, __shfl_xor(lmax, off));
    int wv = tid >> 6, l = tid & 63;
    if (l == 0) sred[wv] = lmax;
    __syncthreads();
    float gmax = fmaxf(fmaxf(sred[0], sred[1]), fmaxf(sred[2], sred[3]));
    float lsum = 0.f;
    #pragma unroll
    for (int jj = 0; jj < 8; ++jj) { x[jj] = __expf(x[jj] - gmax); lsum += x[jj]; }
    #pragma unroll
    for (int off = 1; off < 64; off <<= 1) lsum += __shfl_xor(lsum, off);
    if (l == 0) sred[4 + wv] = lsum;
    __syncthreads();
    float inv = 1.f / (sred[4] + sred[5] + sred[6] + sred[7]);
    #pragma unroll
    for (int jj = 0; jj < 8; ++jj) {
        int s = tid + jj * 256;
        wout[(size_t)b * S_ + s] = x[jj] * inv;
    }
}

// ---------- K4: tpart[ss][b][h] = sum_{s in slice ss} w[b,s] * sent_h[b,s,h] ----------
__global__ void k_wsum(const float* __restrict__ sent, const float* __restrict__ wrow_g,
                       float* __restrict__ tpart) {
    int b  = blockIdx.x >> 4;
    int ss = blockIdx.x & 15;
    int tid = threadIdx.x;
    __shared__ float wrow[128];
    if (tid < 128) wrow[tid] = wrow_g[(size_t)b * S_ + ss * 128 + tid];
    __syncthreads();
    const float* bp = sent + ((size_t)b * S_ + (size_t)ss * 128) * H_ + tid * 2;
    float ax = 0.f, ay = 0.f;
    for (int r0 = 0; r0 < 128; r0 += 8) {
        float2 v[8];
        #pragma unroll
        for (int u = 0; u < 8; ++u)
            v[u] = *(const float2*)(bp + (size_t)(r0 + u) * H_);
        #pragma unroll
        for (int u = 0; u < 8; ++u) {
            float wgt = wrow[r0 + u];
            ax = fmaf(wgt, v[u].x, ax);
            ay = fmaf(wgt, v[u].y, ay);
        }
    }
    float* tp = tpart + ((size_t)ss * B_ + b) * H_ + tid * 2;
    tp[0] = ax; tp[1] = ay;
}

// ---------- K5: att_res[b,h] = Wh_b[h] + sum_h' (sum_ss tpart[ss][b][h']) * Wh_w[h,h'] ----------
__global__ void k_att(const float* __restrict__ tpart, const float* __restrict__ Whw,
                      const float* __restrict__ Whb, float* __restrict__ out) {
    int tid = threadIdx.x;
    int b = blockIdx.x >> 2, q = blockIdx.x & 3;
    __shared__ __attribute__((aligned(16))) float st[H_];
    __shared__ float accs[128];
    for (int i = tid; i < H_; i += 256) {
        float s = 0.f;
        #pragma unroll
        for (int ss = 0; ss < 16; ++ss)
            s += tpart[((size_t)ss * B_ + b) * H_ + i];
        st[i] = s;
    }
    __syncthreads();
    int hh = tid & 127, half = tid >> 7;
    int h = q * 128 + hh;
    const float4* wr = (const float4*)(Whw + (size_t)h * H_) + half * 64;
    const float4* sx = (const float4*)st + half * 64;
    float acc = 0.f;
    #pragma unroll 8
    for (int i = 0; i < 64; ++i) {
        float4 w = wr[i]; float4 x = sx[i];
        acc += w.x * x.x + w.y * x.y + w.z * x.z + w.w * x.w;
    }
    if (half) accs[hh] = acc;
    __syncthreads();
    if (!half) out[(size_t)b * H_ + h] = acc + accs[hh] + Whb[h];
}

extern "C" void kernel_launch(void* const* d_in, const int* in_sizes, int n_in,
                              void* d_out, int out_size, void* d_ws, size_t ws_size,
                              hipStream_t stream) {
    const float* sent_h  = (const float*)d_in[0];
    const float* rel     = (const float*)d_in[1];
    const float* pool    = (const float*)d_in[2];
    const int*   mask    = (const int*)d_in[3];
    const float* Wg_w    = (const float*)d_in[4];
    const float* Wg_b    = (const float*)d_in[5];
    const float* Wh_w    = (const float*)d_in[6];
    const float* Wh_b    = (const float*)d_in[7];
    const float* Wr_w    = (const float*)d_in[8];
    const float* Wr_b    = (const float*)d_in[9];
    const float* alpha_w = (const float*)d_in[10];
    const float* alpha_b = (const float*)d_in[11];
    float* out = (float*)d_out;

    char* ws = (char*)d_ws;
    u16*   whwb    = (u16*)ws;                       // 524288 B
    float* base    = (float*)(ws + 524288);          // 131072 B
    float* partial = (float*)(ws + 524288 + 131072); // 2097152 B
    float* tpart   = (float*)(ws + 524288 + 131072 + 2097152); // 2097152 B

    float* att_out = out;             // [64,512]
    float* w_out   = out + B_ * H_;   // [64,2048]

    k_base<<<dim3(256), dim3(256), 0, stream>>>(rel, pool, Wg_w, Wg_b, Wh_b, Wr_w, Wr_b, Wh_w, base, whwb);
    k_gemm<<<dim3((M_ / 128) * 4), dim3(256), 0, stream>>>(sent_h, whwb, base, alpha_w, partial);
    k_softmax<<<dim3(B_), dim3(256), 0, stream>>>(partial, mask, alpha_b, w_out);
    k_wsum<<<dim3(B_ * 16), dim3(256), 0, stream>>>(sent_h, w_out, tpart);
    k_att<<<dim3(256), dim3(256), 0, stream>>>(tpart, Wh_w, Wh_b, att_out);
}

// Round 10
// 587.581 us; speedup vs baseline: 1.0180x; 1.0180x over previous
//
#include <hip/hip_runtime.h>
#include <cstdint>
#include <cstddef>

#define B_ 64
#define S_ 2048
#define H_ 512
#define R_ 256
#define M_ (B_ * S_)   // 131072
#define NEGV (-1.0e9f)

typedef short short8 __attribute__((ext_vector_type(8)));
typedef unsigned short u16x8 __attribute__((ext_vector_type(8)));
typedef float f32x4 __attribute__((ext_vector_type(4)));
typedef unsigned short u16;

// ---------- helpers ----------
__device__ __forceinline__ u16 f2b(float x) {
    union { float f; uint32_t u; } c; c.f = x;
    uint32_t u = c.u;
    uint32_t r = (u + 0x7fffu + ((u >> 16) & 1u)) >> 16;   // RNE
    return (u16)r;
}
// HW packed f32->bf16 (RNE, identical result to f2b)
__device__ __forceinline__ uint32_t pk2(float lo, float hi) {
    uint32_t r;
    asm("v_cvt_pk_bf16_f32 %0, %1, %2" : "=v"(r) : "v"(lo), "v"(hi));
    return r;
}
__device__ __forceinline__ void load_lds16(const void* g, void* l) {
    __builtin_amdgcn_global_load_lds((__attribute__((address_space(1))) void*)g,
                                     (__attribute__((address_space(3))) void*)l,
                                     16, 0, 0);
}

// ---------- K1: base[b,k] = rel@Wr^T + Wr_b + pool@Wg^T + Wg_b + Wh_b  (+ Wh_w f32->bf16) ----------
__global__ void k_base(const float* __restrict__ rel, const float* __restrict__ pool,
                       const float* __restrict__ Wg_w, const float* __restrict__ Wg_b,
                       const float* __restrict__ Wh_b,
                       const float* __restrict__ Wr_w, const float* __restrict__ Wr_b,
                       const float* __restrict__ whw, float* __restrict__ base,
                       u16* __restrict__ whwb) {
    int tid = threadIdx.x;
    {   // convert Wh_w: 262144 elems = 65536 float4 groups; exactly one per thread
        int gi = blockIdx.x * 256 + tid;
        float4 v = ((const float4*)whw)[gi];
        ushort4 o; o.x = f2b(v.x); o.y = f2b(v.y); o.z = f2b(v.z); o.w = f2b(v.w);
        ((ushort4*)whwb)[gi] = o;
    }
    int b = blockIdx.x >> 2, q = blockIdx.x & 3;
    __shared__ __attribute__((aligned(16))) float srel[R_];
    __shared__ __attribute__((aligned(16))) float spool[H_];
    __shared__ float accs[128];
    srel[tid & 255] = rel[b * R_ + (tid & 255)];
    for (int i = tid; i < H_; i += 256) spool[i] = pool[b * H_ + i];
    __syncthreads();
    int kk = tid & 127, half = tid >> 7;
    int k = q * 128 + kk;
    float acc = 0.f;
    if (half == 0) {
        acc = Wr_b[k] + Wg_b[k] + Wh_b[k];
        const float4* wr = (const float4*)(Wr_w + (size_t)k * R_);
        #pragma unroll 8
        for (int r4 = 0; r4 < R_ / 4; ++r4) {
            float4 w = wr[r4]; float4 x = ((const float4*)srel)[r4];
            acc += w.x * x.x + w.y * x.y + w.z * x.z + w.w * x.w;
        }
        const float4* wg = (const float4*)(Wg_w + (size_t)k * H_);
        #pragma unroll 8
        for (int h4 = 0; h4 < 32; ++h4) {
            float4 w = wg[h4]; float4 x = ((const float4*)spool)[h4];
            acc += w.x * x.x + w.y * x.y + w.z * x.z + w.w * x.w;
        }
    } else {
        const float4* wg = (const float4*)(Wg_w + (size_t)k * H_);
        #pragma unroll 8
        for (int h4 = 32; h4 < 128; ++h4) {
            float4 w = wg[h4]; float4 x = ((const float4*)spool)[h4];
            acc += w.x * x.x + w.y * x.y + w.z * x.z + w.w * x.w;
        }
    }
    if (half) accs[kk] = acc;
    __syncthreads();
    if (!half) base[b * H_ + k] = acc + accs[kk];
}

// ---------- K2: main GEMM -- ROUND-8 version verbatim (best measured: 213 us) ----------
// BK=32, LDS 33.8KB -> 4 blocks/CU. A f32 reg-staged + cvt_pk, B via global_load_lds,
// plain __syncthreads. R9's triple-buffer (272us) and R7's counted-vmcnt (231us) both
// lost to this; keep as control while the tail is restructured.
__launch_bounds__(256, 4)
__global__ void k_gemm(const float* __restrict__ A32,  // [M, 512] f32 (sent_h)
                       const u16* __restrict__ Bw,     // [512, 512] bf16 (Wh_w, B^T layout)
                       const float* __restrict__ base,  // [B_, H_]
                       const float* __restrict__ alpha, // [H_]
                       float* __restrict__ partial)     // [4][M]
{
    const int K = 512;
    const int NT = 16;                  // K-steps (BK=32)
    int j = blockIdx.x;
    int xcd  = j & 7;
    int slot = j >> 3;
    int nb   = slot & 3;
    int mb   = (slot >> 2) * 8 + xcd;   // 0..1023, bijective over grid 4096
    int m0 = mb * 128;
    int n0 = nb * 128;
    int b  = m0 >> 11;   // m0 / S_

    int tid = threadIdx.x;
    int w  = tid >> 6;      // wave 0..3
    int l  = tid & 63;
    int wm = w & 1, wn = w >> 1;
    int lr = l & 15;        // frag row within 16-row chunk / C col
    int lq = l >> 4;        // quad

    __shared__ __attribute__((aligned(16))) u16 smA[2][128 * 32];   // 2 x 8 KB
    __shared__ __attribute__((aligned(16))) u16 smB[2][128 * 32];   // 2 x 8 KB
    __shared__ float red[2][2][64];                                 // 1 KB

    f32x4 zero = {0.f, 0.f, 0.f, 0.f};
    f32x4 acc[4][4];
    #pragma unroll
    for (int i = 0; i < 4; ++i)
        #pragma unroll
        for (int jj = 0; jj < 4; ++jj) acc[i][jj] = zero;

    int arow[2];
    #pragma unroll
    for (int i = 0; i < 2; ++i) arow[i] = (w * 2 + i) * 16 + lr;

    float4 av[2][2];   // in-flight A f32 (16 VGPR)

    auto LOAD_A = [&](int kt) {
        int k0 = kt * 32;
        #pragma unroll
        for (int i = 0; i < 2; ++i) {
            const float4* ga = (const float4*)(A32 + (size_t)(m0 + arow[i]) * K + k0 + lq * 8);
            av[i][0] = ga[0];
            av[i][1] = ga[1];
        }
    };
    auto WRITE_A = [&](int buf) {
        #pragma unroll
        for (int i = 0; i < 2; ++i) {
            uint4 pv;
            pv.x = pk2(av[i][0].x, av[i][0].y);
            pv.y = pk2(av[i][0].z, av[i][0].w);
            pv.z = pk2(av[i][1].x, av[i][1].y);
            pv.w = pk2(av[i][1].z, av[i][1].w);
            *(uint4*)(smA[buf] + (w * 2 + i) * 512 + l * 8) = pv;
        }
    };
    auto STAGE_B = [&](int buf, int kt) {
        int k0 = kt * 32;
        #pragma unroll
        for (int i = 0; i < 2; ++i) {
            int c = w * 2 + i;
            const u16* gb = Bw + (size_t)(n0 + c * 16 + lr) * K + k0 + lq * 8;
            load_lds16(gb, smB[buf] + c * 512);
        }
    };

    LOAD_A(0);
    STAGE_B(0, 0);
    WRITE_A(0);
    __syncthreads();

    #pragma unroll
    for (int kt = 0; kt < NT; ++kt) {
        int cur = kt & 1;
        if (kt < NT - 1) {
            LOAD_A(kt + 1);
            STAGE_B(cur ^ 1, kt + 1);
        }
        __builtin_amdgcn_s_setprio(1);
        {
            short8 af[4], bf[4];
            #pragma unroll
            for (int mi = 0; mi < 4; ++mi)
                af[mi] = *(const short8*)(smA[cur] + (wm * 4 + mi) * 512 + l * 8);
            #pragma unroll
            for (int ni = 0; ni < 4; ++ni)
                bf[ni] = *(const short8*)(smB[cur] + (wn * 4 + ni) * 512 + l * 8);
            #pragma unroll
            for (int mi = 0; mi < 4; ++mi)
                #pragma unroll
                for (int ni = 0; ni < 4; ++ni)
                    acc[mi][ni] = __builtin_amdgcn_mfma_f32_16x16x32_bf16(af[mi], bf[ni], acc[mi][ni], 0, 0, 0);
        }
        __builtin_amdgcn_s_setprio(0);
        if (kt < NT - 1) WRITE_A(cur ^ 1);
        __syncthreads();
    }

    // epilogue: sum_n tanh(acc + base[b,n]) * alpha[n] = sum(a) - sum 2a/(exp2(C2*v)+1)
    const float C2 = 2.8853900817779268f;   // 2*log2(e)
    float base2[4], a2[4];
    float asum = 0.f;
    #pragma unroll
    for (int ni = 0; ni < 4; ++ni) {
        int n = n0 + wn * 64 + ni * 16 + lr;
        base2[ni] = C2 * base[b * H_ + n];
        float al  = alpha[n];
        a2[ni] = 2.0f * al;
        asum  += al;
    }
    #pragma unroll
    for (int mi = 0; mi < 4; ++mi) {
        #pragma unroll
        for (int r = 0; r < 4; ++r) {
            float s = asum;
            #pragma unroll
            for (int ni = 0; ni < 4; ++ni) {
                float f  = fmaf(acc[mi][ni][r], C2, base2[ni]);
                float e  = __builtin_amdgcn_exp2f(f);
                float rr = __builtin_amdgcn_rcpf(e + 1.0f);
                s = fmaf(-a2[ni], rr, s);
            }
            s += __shfl_xor(s, 1);
            s += __shfl_xor(s, 2);
            s += __shfl_xor(s, 4);
            s += __shfl_xor(s, 8);
            if (lr == 0) red[wm][wn][mi * 16 + lq * 4 + r] = s;
        }
    }
    __syncthreads();
    if (tid < 128) {
        int wmi = tid >> 6, row = tid & 63;
        float sum = red[wmi][0][row] + red[wmi][1][row];
        partial[(size_t)nb * M_ + m0 + wmi * 64 + row] = sum;
    }
}

// ---------- K3: fused tail -- softmax + wsum-slice + mini-gemm + atomic reduce ----------
// Grid 64b x 8 slices, 256 thr. Launch-count probe: replaces softmax+wsum+att (3 launches
// + tpart round-trip) with ONE kernel. Each block: (1) full softmax for its b (32KB read,
// L2-hit for 7/8 blocks -- redundant but trivial; slice 0 writes w_out), (2) weighted sum
// over its contiguous 256-row s-slice of sent_h (512KB sequential), (3) t_sl @ Wh^T
// (Whw L2/L3-resident) with one f32 atomicAdd per output (8-way contention).
__global__ void k_tail(const float* __restrict__ partial, const int* __restrict__ mask,
                       const float* __restrict__ alpha_b, const float* __restrict__ sent,
                       const float* __restrict__ Whw, const float* __restrict__ Whb,
                       float* __restrict__ wout, float* __restrict__ att_out) {
    int b  = blockIdx.x >> 3;
    int sl = blockIdx.x & 7;
    int tid = threadIdx.x;
    __shared__ float sred[8];
    __shared__ float sw[256];                                  // this slice's weights
    __shared__ __attribute__((aligned(16))) float st[H_];      // t_sl
    float x[8];
    float ab = alpha_b[0];
    float lmax = -3.0e38f;
    #pragma unroll
    for (int jj = 0; jj < 8; ++jj) {
        int s = tid + jj * 256;
        size_t m = (size_t)b * S_ + s;
        float v = partial[m] + partial[(size_t)M_ + m] + partial[2 * (size_t)M_ + m] + partial[3 * (size_t)M_ + m] + ab;
        if (mask[b * S_ + s] == 0) v = NEGV;
        x[jj] = v;
        lmax = fmaxf(lmax, v);
    }
    #pragma unroll
    for (int off = 1; off < 64; off <<= 1) lmax = fmaxf(lmax, __shfl_xor(lmax, off));
    int wv = tid >> 6, l = tid & 63;
    if (l == 0) sred[wv] = lmax;
    __syncthreads();
    float gmax = fmaxf(fmaxf(sred[0], sred[1]), fmaxf(sred[2], sred[3]));
    float lsum = 0.f;
    #pragma unroll
    for (int jj = 0; jj < 8; ++jj) { x[jj] = __expf(x[jj] - gmax); lsum += x[jj]; }
    #pragma unroll
    for (int off = 1; off < 64; off <<= 1) lsum += __shfl_xor(lsum, off);
    if (l == 0) sred[4 + wv] = lsum;
    __syncthreads();
    float inv = 1.f / (sred[4] + sred[5] + sred[6] + sred[7]);
    #pragma unroll
    for (int jj = 0; jj < 8; ++jj) {
        float wvv = x[jj] * inv;
        if (sl == 0) wout[(size_t)b * S_ + tid + jj * 256] = wvv;
        if (jj == sl) sw[tid] = wvv;     // s = sl*256 + tid
    }
    __syncthreads();

    // (2) wsum over rows sl*256 .. sl*256+256, cols 2tid, 2tid+1 (contiguous 2KB/row)
    const float* bp = sent + ((size_t)b * S_ + (size_t)sl * 256) * H_ + tid * 2;
    float ax = 0.f, ay = 0.f;
    for (int r0 = 0; r0 < 256; r0 += 8) {
        float2 v[8];
        #pragma unroll
        for (int u = 0; u < 8; ++u)
            v[u] = *(const float2*)(bp + (size_t)(r0 + u) * H_);
        #pragma unroll
        for (int u = 0; u < 8; ++u) {
            float wgt = sw[r0 + u];
            ax = fmaf(wgt, v[u].x, ax);
            ay = fmaf(wgt, v[u].y, ay);
        }
    }
    st[tid * 2]     = ax;
    st[tid * 2 + 1] = ay;
    __syncthreads();

    // (3) mini-gemm: att_contrib[h] = sum_h' st[h'] * Whw[h][h'], h = tid, tid+256
    #pragma unroll
    for (int rep = 0; rep < 2; ++rep) {
        int h = tid + rep * 256;
        const float4* wr = (const float4*)(Whw + (size_t)h * H_);
        float acc = (sl == 0) ? Whb[h] : 0.f;
        #pragma unroll 8
        for (int i = 0; i < 128; ++i) {
            float4 wv2 = wr[i]; float4 xv = ((const float4*)st)[i];
            acc += wv2.x * xv.x + wv2.y * xv.y + wv2.z * xv.z + wv2.w * xv.w;
        }
        atomicAdd(att_out + (size_t)b * H_ + h, acc);
    }
}

extern "C" void kernel_launch(void* const* d_in, const int* in_sizes, int n_in,
                              void* d_out, int out_size, void* d_ws, size_t ws_size,
                              hipStream_t stream) {
    const float* sent_h  = (const float*)d_in[0];
    const float* rel     = (const float*)d_in[1];
    const float* pool    = (const float*)d_in[2];
    const int*   mask    = (const int*)d_in[3];
    const float* Wg_w    = (const float*)d_in[4];
    const float* Wg_b    = (const float*)d_in[5];
    const float* Wh_w    = (const float*)d_in[6];
    const float* Wh_b    = (const float*)d_in[7];
    const float* Wr_w    = (const float*)d_in[8];
    const float* Wr_b    = (const float*)d_in[9];
    const float* alpha_w = (const float*)d_in[10];
    const float* alpha_b = (const float*)d_in[11];
    float* out = (float*)d_out;

    char* ws = (char*)d_ws;
    u16*   whwb    = (u16*)ws;                       // 524288 B
    float* base    = (float*)(ws + 524288);          // 131072 B
    float* partial = (float*)(ws + 524288 + 131072); // 2097152 B

    float* att_out = out;             // [64,512]
    float* w_out   = out + B_ * H_;   // [64,2048]

    hipMemsetAsync(att_out, 0, (size_t)B_ * H_ * sizeof(float), stream);
    k_base<<<dim3(256), dim3(256), 0, stream>>>(rel, pool, Wg_w, Wg_b, Wh_b, Wr_w, Wr_b, Wh_w, base, whwb);
    k_gemm<<<dim3((M_ / 128) * 4), dim3(256), 0, stream>>>(sent_h, whwb, base, alpha_w, partial);
    k_tail<<<dim3(B_ * 8), dim3(256), 0, stream>>>(partial, mask, alpha_b, sent_h, Wh_w, Wh_b, w_out, att_out);
}

// Round 11
// 524.398 us; speedup vs baseline: 1.1406x; 1.1205x over previous
//
#include <hip/hip_runtime.h>
#include <cstdint>
#include <cstddef>

#define B_ 64
#define S_ 2048
#define H_ 512
#define R_ 256
#define M_ (B_ * S_)   // 131072
#define NEGV (-1.0e9f)

typedef short short8 __attribute__((ext_vector_type(8)));
typedef unsigned short u16x8 __attribute__((ext_vector_type(8)));
typedef float f32x4 __attribute__((ext_vector_type(4)));
typedef unsigned short u16;

#define VMCNT(N)  asm volatile("s_waitcnt vmcnt(" #N ")" ::: "memory")
#define LGKM0()   asm volatile("s_waitcnt lgkmcnt(0)" ::: "memory")
#define SB0()     __builtin_amdgcn_sched_barrier(0)

// ---------- helpers ----------
__device__ __forceinline__ u16 f2b(float x) {
    union { float f; uint32_t u; } c; c.f = x;
    uint32_t u = c.u;
    uint32_t r = (u + 0x7fffu + ((u >> 16) & 1u)) >> 16;   // RNE
    return (u16)r;
}
// HW packed f32->bf16 (RNE, identical result to f2b)
__device__ __forceinline__ uint32_t pk2(float lo, float hi) {
    uint32_t r;
    asm("v_cvt_pk_bf16_f32 %0, %1, %2" : "=v"(r) : "v"(lo), "v"(hi));
    return r;
}
// asm global load: opaque to the allocator -> cannot be sunk (R5 failure mode), proven R7
__device__ __forceinline__ float4 gload4(const float4* p) {
    float4 d;
    asm volatile("global_load_dwordx4 %0, %1, off" : "=v"(d) : "v"(p));
    return d;
}
__device__ __forceinline__ void load_lds16(const void* g, void* l) {
    __builtin_amdgcn_global_load_lds((__attribute__((address_space(1))) void*)g,
                                     (__attribute__((address_space(3))) void*)l,
                                     16, 0, 0);
}

// ---------- K1: base[b,k] = rel@Wr^T + Wr_b + pool@Wg^T + Wg_b + Wh_b  (+ Wh_w f32->bf16) ----------
__global__ void k_base(const float* __restrict__ rel, const float* __restrict__ pool,
                       const float* __restrict__ Wg_w, const float* __restrict__ Wg_b,
                       const float* __restrict__ Wh_b,
                       const float* __restrict__ Wr_w, const float* __restrict__ Wr_b,
                       const float* __restrict__ whw, float* __restrict__ base,
                       u16* __restrict__ whwb) {
    int tid = threadIdx.x;
    {   // convert Wh_w: 262144 elems = 65536 float4 groups; exactly one per thread
        int gi = blockIdx.x * 256 + tid;
        float4 v = ((const float4*)whw)[gi];
        ushort4 o; o.x = f2b(v.x); o.y = f2b(v.y); o.z = f2b(v.z); o.w = f2b(v.w);
        ((ushort4*)whwb)[gi] = o;
    }
    int b = blockIdx.x >> 2, q = blockIdx.x & 3;
    __shared__ __attribute__((aligned(16))) float srel[R_];
    __shared__ __attribute__((aligned(16))) float spool[H_];
    __shared__ float accs[128];
    srel[tid & 255] = rel[b * R_ + (tid & 255)];
    for (int i = tid; i < H_; i += 256) spool[i] = pool[b * H_ + i];
    __syncthreads();
    int kk = tid & 127, half = tid >> 7;
    int k = q * 128 + kk;
    float acc = 0.f;
    if (half == 0) {
        acc = Wr_b[k] + Wg_b[k] + Wh_b[k];
        const float4* wr = (const float4*)(Wr_w + (size_t)k * R_);
        #pragma unroll 8
        for (int r4 = 0; r4 < R_ / 4; ++r4) {
            float4 w = wr[r4]; float4 x = ((const float4*)srel)[r4];
            acc += w.x * x.x + w.y * x.y + w.z * x.z + w.w * x.w;
        }
        const float4* wg = (const float4*)(Wg_w + (size_t)k * H_);
        #pragma unroll 8
        for (int h4 = 0; h4 < 32; ++h4) {
            float4 w = wg[h4]; float4 x = ((const float4*)spool)[h4];
            acc += w.x * x.x + w.y * x.y + w.z * x.z + w.w * x.w;
        }
    } else {
        const float4* wg = (const float4*)(Wg_w + (size_t)k * H_);
        #pragma unroll 8
        for (int h4 = 32; h4 < 128; ++h4) {
            float4 w = wg[h4]; float4 x = ((const float4*)spool)[h4];
            acc += w.x * x.x + w.y * x.y + w.z * x.z + w.w * x.w;
        }
    }
    if (half) accs[kk] = acc;
    __syncthreads();
    if (!half) base[b * H_ + k] = acc + accs[kk];
}

// ---------- K2: main GEMM, 256x256-tile 8-wave phase-split port (guide's m201 schedule) ----------
// 512 thr = 8 waves (2M x 4N), per-wave output 128x64 (acc[8][4]). BK=64, 8 K-tiles.
// 4 phases per tile, each {8 ds_read_b128 -> 16 MFMA (setprio-wrapped)} + s_barrier, so
// waves stagger roles (T3 prereq for T5). Staging interleaved: A f32 asm-loads at phase 0,
// B gload_lds at phase 1, ONE VMCNT(4)->cvt+ds_write A->VMCNT(0) per tile (A window = 3
// phases, B = 4 phases; vm queue never drained mid-tile). Chunked lane-linear LDS layout
// (bank-conflict-free, 10 rounds proven). Sync scheme = R5's passed lgkm0+raw-barrier.
__launch_bounds__(512, 1)
__global__ void k_gemm(const float* __restrict__ A32,  // [M, 512] f32 (sent_h)
                       const u16* __restrict__ Bw,     // [512, 512] bf16 (Wh_w, B^T layout)
                       const float* __restrict__ base,  // [B_, H_]
                       const float* __restrict__ alpha, // [H_]
                       float* __restrict__ partial)     // [2][M]
{
    const int K = 512;
    int j = blockIdx.x;
    int sid = (j & 7) * 128 + (j >> 3);   // chunked per-XCD, bijective (1024 % 8 == 0)
    int nb  = sid & 1;
    int mbt = sid >> 1;                   // 0..511
    int m0 = mbt * 256;
    int n0 = nb * 256;
    int b  = m0 >> 11;

    int tid = threadIdx.x;
    int w  = tid >> 6;          // wave 0..7
    int l  = tid & 63;
    int wm = w & 1, wn = w >> 1;   // wn 0..3
    int lr = l & 15;            // C col / frag row
    int lq = l >> 4;            // quad

    // chunk c (0..31): mf = c>>1 (16-row group), kc = c&1 (32-col half). 512 elems each.
    __shared__ __attribute__((aligned(16))) u16 smA[2][32 * 512];   // 2 x 32 KB
    __shared__ __attribute__((aligned(16))) u16 smB[2][32 * 512];   // 2 x 32 KB
    __shared__ float red[2][4][128];                                // 4 KB

    f32x4 zero = {0.f, 0.f, 0.f, 0.f};
    f32x4 acc[8][4];
    #pragma unroll
    for (int i = 0; i < 8; ++i)
        #pragma unroll
        for (int jj = 0; jj < 4; ++jj) acc[i][jj] = zero;

    float4 av[4][2];   // in-flight A f32, 32 VGPR (4 chunks x 32B per wave)

    // wave w stages chunks c = w*4 .. w*4+3
    auto LOAD_A = [&](int t) {         // 8 asm loads, program-ordered, oldest in queue
        int k0 = t * 64;
        #pragma unroll
        for (int i = 0; i < 4; ++i) {
            int c = w * 4 + i;
            const float4* ga = (const float4*)(A32 + (size_t)(m0 + (c >> 1) * 16 + lr) * K
                                               + k0 + (c & 1) * 32 + lq * 8);
            av[i][0] = gload4(ga);
            av[i][1] = gload4(ga + 1);
        }
    };
    auto WRITE_A = [&](int buf) {
        #pragma unroll
        for (int i = 0; i < 4; ++i) {
            uint4 pv;
            pv.x = pk2(av[i][0].x, av[i][0].y);
            pv.y = pk2(av[i][0].z, av[i][0].w);
            pv.z = pk2(av[i][1].x, av[i][1].y);
            pv.w = pk2(av[i][1].z, av[i][1].w);
            *(uint4*)(smA[buf] + (w * 4 + i) * 512 + l * 8) = pv;
        }
    };
    auto STAGE_B = [&](int buf, int t) {   // 4 gload_lds (dest: wave-uniform + lane*16)
        int k0 = t * 64;
        #pragma unroll
        for (int i = 0; i < 4; ++i) {
            int c = w * 4 + i;
            const u16* gb = Bw + (size_t)(n0 + (c >> 1) * 16 + lr) * K
                            + k0 + (c & 1) * 32 + lq * 8;
            load_lds16(gb, smB[buf] + c * 512);
        }
    };
    // one phase: 4 af + 4 bf ds_read_b128, 16 MFMA (compiler inserts lgkm waits)
    auto PHASE = [&](int cur, int kc, int mh) {
        short8 af[4], bf[4];
        #pragma unroll
        for (int jj = 0; jj < 4; ++jj)
            af[jj] = *(const short8*)(smA[cur] + ((wm * 8 + mh * 4 + jj) * 2 + kc) * 512 + l * 8);
        #pragma unroll
        for (int n = 0; n < 4; ++n)
            bf[n] = *(const short8*)(smB[cur] + ((wn * 4 + n) * 2 + kc) * 512 + l * 8);
        __builtin_amdgcn_s_setprio(1);
        #pragma unroll
        for (int jj = 0; jj < 4; ++jj)
            #pragma unroll
            for (int n = 0; n < 4; ++n)
                acc[mh * 4 + jj][n] = __builtin_amdgcn_mfma_f32_16x16x32_bf16(af[jj], bf[n], acc[mh * 4 + jj][n], 0, 0, 0);
        __builtin_amdgcn_s_setprio(0);
    };

    // prologue: stage tile 0 into buf 0. queue: A8 then B4.
    LOAD_A(0);
    STAGE_B(0, 0);
    VMCNT(4); SB0();                 // A landed (oldest 8); B may ride
    WRITE_A(0);
    VMCNT(0); LGKM0();
    __builtin_amdgcn_s_barrier();
    SB0();

    #pragma unroll
    for (int t = 0; t < 8; ++t) {
        const int cur = t & 1, nxt = cur ^ 1;
        if (t < 7) LOAD_A(t + 1);            // A(t+1) -> regs, oldest in queue
        PHASE(cur, 0, 0);
        __builtin_amdgcn_s_barrier();
        if (t < 7) STAGE_B(nxt, t + 1);      // B(t+1) -> LDS, behind A in queue
        PHASE(cur, 0, 1);
        __builtin_amdgcn_s_barrier();
        PHASE(cur, 1, 0);
        __builtin_amdgcn_s_barrier();
        PHASE(cur, 1, 1);
        if (t < 7) {
            VMCNT(4); SB0();                 // A(t+1) landed; B(t+1) may ride
            WRITE_A(nxt);
            VMCNT(0);                        // B(t+1) landed before buffer swap
        }
        LGKM0();                             // own ds_writes drained
        __builtin_amdgcn_s_barrier();
        SB0();
    }

    // epilogue: sum_n tanh(acc + base[b,n]) * alpha[n] = sum(a) - sum 2a/(exp2(C2*v)+1)
    const float C2 = 2.8853900817779268f;   // 2*log2(e)
    float base2[4], a2[4];
    float asum = 0.f;
    #pragma unroll
    for (int ni = 0; ni < 4; ++ni) {
        int n = n0 + wn * 64 + ni * 16 + lr;
        base2[ni] = C2 * base[b * H_ + n];
        float al  = alpha[n];
        a2[ni] = 2.0f * al;
        asum  += al;
    }
    #pragma unroll
    for (int mi = 0; mi < 8; ++mi) {
        #pragma unroll
        for (int r = 0; r < 4; ++r) {
            float s = asum;
            #pragma unroll
            for (int ni = 0; ni < 4; ++ni) {
                float f  = fmaf(acc[mi][ni][r], C2, base2[ni]);
                float e  = __builtin_amdgcn_exp2f(f);
                float rr = __builtin_amdgcn_rcpf(e + 1.0f);
                s = fmaf(-a2[ni], rr, s);
            }
            s += __shfl_xor(s, 1);
            s += __shfl_xor(s, 2);
            s += __shfl_xor(s, 4);
            s += __shfl_xor(s, 8);
            if (lr == 0) red[wm][wn][mi * 16 + lq * 4 + r] = s;
        }
    }
    __syncthreads();
    if (tid < 256) {
        int wm2 = tid >> 7, row = tid & 127;
        float sum = red[wm2][0][row] + red[wm2][1][row] + red[wm2][2][row] + red[wm2][3][row];
        partial[(size_t)nb * M_ + m0 + wm2 * 128 + row] = sum;
    }
}

// ---------- K3: softmax over S per b (partial now [2][M]) ----------
__global__ void k_softmax(const float* __restrict__ partial, const int* __restrict__ mask,
                          const float* __restrict__ alpha_b, float* __restrict__ wout) {
    int b = blockIdx.x;
    int tid = threadIdx.x;
    __shared__ float sred[8];
    float x[8];
    float ab = alpha_b[0];
    float lmax = -3.0e38f;
    #pragma unroll
    for (int jj = 0; jj < 8; ++jj) {
        int s = tid + jj * 256;
        size_t m = (size_t)b * S_ + s;
        float v = partial[m] + partial[(size_t)M_ + m] + ab;
        if (mask[b * S_ + s] == 0) v = NEGV;
        x[jj] = v;
        lmax = fmaxf(lmax, v);
    }
    #pragma unroll
    for (int off = 1; off < 64; off <<= 1) lmax = fmaxf(lmax, __shfl_xor(lmax, off));
    int wv = tid >> 6, l = tid & 63;
    if (l == 0) sred[wv] = lmax;
    __syncthreads();
    float gmax = fmaxf(fmaxf(sred[0], sred[1]), fmaxf(sred[2], sred[3]));
    float lsum = 0.f;
    #pragma unroll
    for (int jj = 0; jj < 8; ++jj) { x[jj] = __expf(x[jj] - gmax); lsum += x[jj]; }
    #pragma unroll
    for (int off = 1; off < 64; off <<= 1) lsum += __shfl_xor(lsum, off);
    if (l == 0) sred[4 + wv] = lsum;
    __syncthreads();
    float inv = 1.f / (sred[4] + sred[5] + sred[6] + sred[7]);
    #pragma unroll
    for (int jj = 0; jj < 8; ++jj) {
        int s = tid + jj * 256;
        wout[(size_t)b * S_ + s] = x[jj] * inv;
    }
}

// ---------- K4: tpart[ss][b][h] = sum_{s in slice ss} w[b,s] * sent_h[b,s,h] ----------
__global__ void k_wsum(const float* __restrict__ sent, const float* __restrict__ wrow_g,
                       float* __restrict__ tpart) {
    int b  = blockIdx.x >> 4;
    int ss = blockIdx.x & 15;
    int tid = threadIdx.x;
    __shared__ float wrow[128];
    if (tid < 128) wrow[tid] = wrow_g[(size_t)b * S_ + ss * 128 + tid];
    __syncthreads();
    const float* bp = sent + ((size_t)b * S_ + (size_t)ss * 128) * H_ + tid * 2;
    float ax = 0.f, ay = 0.f;
    for (int r0 = 0; r0 < 128; r0 += 8) {
        float2 v[8];
        #pragma unroll
        for (int u = 0; u < 8; ++u)
            v[u] = *(const float2*)(bp + (size_t)(r0 + u) * H_);
        #pragma unroll
        for (int u = 0; u < 8; ++u) {
            float wgt = wrow[r0 + u];
            ax = fmaf(wgt, v[u].x, ax);
            ay = fmaf(wgt, v[u].y, ay);
        }
    }
    float* tp = tpart + ((size_t)ss * B_ + b) * H_ + tid * 2;
    tp[0] = ax; tp[1] = ay;
}

// ---------- K5: att_res[b,h] = Wh_b[h] + sum_h' (sum_ss tpart[ss][b][h']) * Wh_w[h,h'] ----------
__global__ void k_att(const float* __restrict__ tpart, const float* __restrict__ Whw,
                      const float* __restrict__ Whb, float* __restrict__ out) {
    int tid = threadIdx.x;
    int b = blockIdx.x >> 2, q = blockIdx.x & 3;
    __shared__ __attribute__((aligned(16))) float st[H_];
    __shared__ float accs[128];
    for (int i = tid; i < H_; i += 256) {
        float s = 0.f;
        #pragma unroll
        for (int ss = 0; ss < 16; ++ss)
            s += tpart[((size_t)ss * B_ + b) * H_ + i];
        st[i] = s;
    }
    __syncthreads();
    int hh = tid & 127, half = tid >> 7;
    int h = q * 128 + hh;
    const float4* wr = (const float4*)(Whw + (size_t)h * H_) + half * 64;
    const float4* sx = (const float4*)st + half * 64;
    float acc = 0.f;
    #pragma unroll 8
    for (int i = 0; i < 64; ++i) {
        float4 w = wr[i]; float4 x = sx[i];
        acc += w.x * x.x + w.y * x.y + w.z * x.z + w.w * x.w;
    }
    if (half) accs[hh] = acc;
    __syncthreads();
    if (!half) out[(size_t)b * H_ + h] = acc + accs[hh] + Whb[h];
}

extern "C" void kernel_launch(void* const* d_in, const int* in_sizes, int n_in,
                              void* d_out, int out_size, void* d_ws, size_t ws_size,
                              hipStream_t stream) {
    const float* sent_h  = (const float*)d_in[0];
    const float* rel     = (const float*)d_in[1];
    const float* pool    = (const float*)d_in[2];
    const int*   mask    = (const int*)d_in[3];
    const float* Wg_w    = (const float*)d_in[4];
    const float* Wg_b    = (const float*)d_in[5];
    const float* Wh_w    = (const float*)d_in[6];
    const float* Wh_b    = (const float*)d_in[7];
    const float* Wr_w    = (const float*)d_in[8];
    const float* Wr_b    = (const float*)d_in[9];
    const float* alpha_w = (const float*)d_in[10];
    const float* alpha_b = (const float*)d_in[11];
    float* out = (float*)d_out;

    char* ws = (char*)d_ws;
    u16*   whwb    = (u16*)ws;                       // 524288 B
    float* base    = (float*)(ws + 524288);          // 131072 B
    float* partial = (float*)(ws + 524288 + 131072); // [2][M] = 1048576 B
    float* tpart   = (float*)(ws + 524288 + 131072 + 1048576); // 2097152 B

    float* att_out = out;             // [64,512]
    float* w_out   = out + B_ * H_;   // [64,2048]

    k_base<<<dim3(256), dim3(256), 0, stream>>>(rel, pool, Wg_w, Wg_b, Wh_b, Wr_w, Wr_b, Wh_w, base, whwb);
    k_gemm<<<dim3(1024), dim3(512), 0, stream>>>(sent_h, whwb, base, alpha_w, partial);
    k_softmax<<<dim3(B_), dim3(256), 0, stream>>>(partial, mask, alpha_b, w_out);
    k_wsum<<<dim3(B_ * 16), dim3(256), 0, stream>>>(sent_h, w_out, tpart);
    k_att<<<dim3(256), dim3(256), 0, stream>>>(tpart, Wh_w, Wh_b, att_out);
}